// Round 2
// baseline (597.491 us; speedup 1.0000x reference)
//
#include <hip/hip_runtime.h>
#include <hip/hip_cooperative_groups.h>

namespace cg = cooperative_groups;

// PolyConv: out[n,:] = Wx@x[n] + Wl@x[l[n]] + Wr@x[r[n]] + b   (N=1e6, D=64, O=64)
//
// R3 post-mortem: two-pass bf16 (convert 80us + gather 160us) == R2 single-pass
// f32 (230us). Both serve ~1032MB at the LLC level at ~4.3-4.5 TB/s — the
// conversion round-trip (128W+128R) exactly cancels the f32-gather savings.
// R4 discriminates T-A (LLC service ceiling -> at floor) vs T-B (HBM random
// misses -> residency timing helps): fuse convert + grid.sync + compute in one
// cooperative kernel so phase B runs while xb is maximally LLC-resident.
// Micro: swapped MFMA operands -> lane holds 4 consecutive out floats ->
// 4x fewer store insts (4 NT dwordx4/tile), bias init = 1 vector load.

typedef __bf16 bf16x8 __attribute__((ext_vector_type(8)));
typedef float floatx4 __attribute__((ext_vector_type(4)));

#define D 64
#define O 64
#define K3 192

// ---------------- convert helper: 16 floats -> 8+8 bf16, NT loads ----------------
__device__ __forceinline__ void cvt_chunk(const float* __restrict__ x,
                                          __bf16* __restrict__ xb, long i) {
    floatx4 a = __builtin_nontemporal_load((const floatx4*)x + 2 * i);
    floatx4 b = __builtin_nontemporal_load((const floatx4*)x + 2 * i + 1);
    bf16x8 f;
    f[0] = (__bf16)a[0]; f[1] = (__bf16)a[1];
    f[2] = (__bf16)a[2]; f[3] = (__bf16)a[3];
    f[4] = (__bf16)b[0]; f[5] = (__bf16)b[1];
    f[6] = (__bf16)b[2]; f[7] = (__bf16)b[3];
    ((bf16x8*)xb)[i] = f;   // normal store: keep xb LLC-resident for phase B
}

// ---------------- W fragments + bias (swapped layout) ----------------
// bfrag[ks][ct]: lane(col,quad) holds W[ct*16+col][ks*32+quad*8+j]  (A operand)
// bi4[ct]: lane(quad) holds bias[ct*16+quad*4 .. +3]                 (acc init)
__device__ __forceinline__ void load_wfrags(bf16x8 (&bfrag)[6][4], floatx4 (&bi4)[4],
                                            const float* __restrict__ W,
                                            const float* __restrict__ bias,
                                            int col, int quad) {
#pragma unroll
    for (int ct = 0; ct < 4; ++ct) {
        const float* wrow = W + (size_t)(ct * 16 + col) * K3 + quad * 8;
#pragma unroll
        for (int ks = 0; ks < 6; ++ks) {
            floatx4 w0 = *(const floatx4*)(wrow + ks * 32);
            floatx4 w1 = *(const floatx4*)(wrow + ks * 32 + 4);
            bf16x8 f;
            f[0] = (__bf16)w0[0]; f[1] = (__bf16)w0[1];
            f[2] = (__bf16)w0[2]; f[3] = (__bf16)w0[3];
            f[4] = (__bf16)w1[0]; f[5] = (__bf16)w1[1];
            f[6] = (__bf16)w1[2]; f[7] = (__bf16)w1[3];
            bfrag[ks][ct] = f;
        }
        bi4[ct] = *(const floatx4*)(bias + ct * 16 + quad * 4);
    }
}

// ---------------- bf16 gather: 6x16B, each load IS an MFMA B-fragment ----------------
__device__ __forceinline__ void issue_gather_bf16(bf16x8 (&v)[6],
                                                  const __bf16* __restrict__ xb,
                                                  int item, int li, int ri, int quad) {
    const __bf16* px = xb + (size_t)item * D + quad * 8;
    const __bf16* pl = xb + (size_t)li   * D + quad * 8;
    const __bf16* pr = xb + (size_t)ri   * D + quad * 8;
    v[0] = *(const bf16x8*)(px); v[1] = *(const bf16x8*)(px + 32);
    v[2] = *(const bf16x8*)(pl); v[3] = *(const bf16x8*)(pl + 32);
    v[4] = *(const bf16x8*)(pr); v[5] = *(const bf16x8*)(pr + 32);
}

// ---------------- swapped MFMA: D[o][item]; lane holds 4 consecutive outs ----------------
__device__ __forceinline__ void compute_store_swapped(const bf16x8 (&v)[6],
                                                      const bf16x8 (&bfrag)[6][4],
                                                      const floatx4 (&bi4)[4],
                                                      float* __restrict__ out,
                                                      int base, int col, int quad) {
    floatx4 acc[4];
#pragma unroll
    for (int ct = 0; ct < 4; ++ct) acc[ct] = bi4[ct];
#pragma unroll
    for (int ct = 0; ct < 4; ++ct)
#pragma unroll
        for (int ks = 0; ks < 6; ++ks)
            acc[ct] = __builtin_amdgcn_mfma_f32_16x16x32_bf16(
                bfrag[ks][ct], v[ks], acc[ct], 0, 0, 0);
    // lane(col,quad), reg r of acc[ct] = out[base+col][ct*16 + quad*4 + r]
    float* op = out + (size_t)(base + col) * O + quad * 4;
#pragma unroll
    for (int ct = 0; ct < 4; ++ct)
        __builtin_nontemporal_store(acc[ct], (floatx4*)(op + ct * 16));
}

// ---------------- phase B main loop (double-buffered gathers + idx prefetch) ----------------
__device__ __forceinline__ void gather_compute_loop(const __bf16* __restrict__ xb,
                                                    const int* __restrict__ lidx,
                                                    const int* __restrict__ ridx,
                                                    const bf16x8 (&bfrag)[6][4],
                                                    const floatx4 (&bi4)[4],
                                                    float* __restrict__ out,
                                                    int n_tiles, int stride,
                                                    int wave_id, int col, int quad) {
    int t = wave_id;
    if (t >= n_tiles) return;           // wave-uniform

    bf16x8 va[6], vb[6];
    int li_n = 0, ri_n = 0;

    {
        int item = t * 16 + col;
        int li = lidx[item], ri = ridx[item];
        issue_gather_bf16(va, xb, item, li, ri, quad);
    }
    int t1 = t + stride;
    if (t1 < n_tiles) { li_n = lidx[t1 * 16 + col]; ri_n = ridx[t1 * 16 + col]; }

    while (true) {
        // ---- phase A: state in va, issue next into vb ----
        if (t1 < n_tiles) {
            issue_gather_bf16(vb, xb, t1 * 16 + col, li_n, ri_n, quad);
            int t2 = t1 + stride;
            if (t2 < n_tiles) { li_n = lidx[t2 * 16 + col]; ri_n = ridx[t2 * 16 + col]; }
        }
        compute_store_swapped(va, bfrag, bi4, out, t * 16, col, quad);
        t = t1; t1 += stride;
        if (t >= n_tiles) break;

        // ---- phase B: state in vb, issue next into va ----
        if (t1 < n_tiles) {
            issue_gather_bf16(va, xb, t1 * 16 + col, li_n, ri_n, quad);
            int t2 = t1 + stride;
            if (t2 < n_tiles) { li_n = lidx[t2 * 16 + col]; ri_n = ridx[t2 * 16 + col]; }
        }
        compute_store_swapped(vb, bfrag, bi4, out, t * 16, col, quad);
        t = t1; t1 += stride;
        if (t >= n_tiles) break;
    }
}

// ---------------- R4: fused cooperative kernel ----------------
__global__ __launch_bounds__(256, 2) void polyconv_fused(
    const float* __restrict__ x,
    const int* __restrict__ lidx,
    const int* __restrict__ ridx,
    const float* __restrict__ W,
    const float* __restrict__ bias,
    float* __restrict__ out,
    __bf16* __restrict__ xb,
    int n_tiles, int total_waves, long n8)
{
    const int lane = threadIdx.x & 63;
    const int wave_id = blockIdx.x * (blockDim.x >> 6) + (threadIdx.x >> 6);
    const int col  = lane & 15;
    const int quad = lane >> 4;

    // ---- phase A: linear f32 -> bf16 convert (streaming) ----
    {
        long i = (long)blockIdx.x * blockDim.x + threadIdx.x;
        const long cstride = (long)gridDim.x * blockDim.x;
        for (; i < n8; i += cstride) cvt_chunk(x, xb, i);
    }

    // W fragments + bias: independent of phase A, overlaps its drain
    bf16x8 bfrag[6][4];
    floatx4 bi4[4];
    load_wfrags(bfrag, bi4, W, bias, col, quad);

    __threadfence();
    cg::this_grid().sync();

    // ---- phase B: gather + MFMA while xb is maximally LLC-resident ----
    gather_compute_loop(xb, lidx, ridx, bfrag, bi4, out,
                        n_tiles, total_waves, wave_id, col, quad);
}

// ---------------- fallback A: two-kernel bf16 path (R3) ----------------
__global__ __launch_bounds__(256) void convert_x_bf16(
    const float* __restrict__ x, __bf16* __restrict__ xb, long n8)
{
    long i = (long)blockIdx.x * 256 + threadIdx.x;
    const long stride = (long)gridDim.x * 256;
    for (; i < n8; i += stride) cvt_chunk(x, xb, i);
}

__global__ __launch_bounds__(256, 2) void polyconv_bf16(
    const __bf16* __restrict__ xb,
    const int* __restrict__ lidx,
    const int* __restrict__ ridx,
    const float* __restrict__ W,
    const float* __restrict__ bias,
    float* __restrict__ out,
    int n_tiles, int total_waves)
{
    const int lane = threadIdx.x & 63;
    const int wave_id = blockIdx.x * (blockDim.x >> 6) + (threadIdx.x >> 6);
    const int col  = lane & 15;
    const int quad = lane >> 4;

    bf16x8 bfrag[6][4];
    floatx4 bi4[4];
    load_wfrags(bfrag, bi4, W, bias, col, quad);

    gather_compute_loop(xb, lidx, ridx, bfrag, bi4, out,
                        n_tiles, total_waves, wave_id, col, quad);
}

// ---------------- fallback B: f32 single-pass (R2, unchanged) ----------------
__device__ __forceinline__ void issue_gather_f32(floatx4 (&v)[12], const float* __restrict__ x,
                                                 int item, int li, int ri, int quad) {
    const float* px = x + (size_t)item * D + quad * 8;
    const float* pl = x + (size_t)li   * D + quad * 8;
    const float* pr = x + (size_t)ri   * D + quad * 8;
    v[0]  = *(const floatx4*)(px);      v[1]  = *(const floatx4*)(px + 4);
    v[2]  = *(const floatx4*)(px + 32); v[3]  = *(const floatx4*)(px + 36);
    v[4]  = *(const floatx4*)(pl);      v[5]  = *(const floatx4*)(pl + 4);
    v[6]  = *(const floatx4*)(pl + 32); v[7]  = *(const floatx4*)(pl + 36);
    v[8]  = *(const floatx4*)(pr);      v[9]  = *(const floatx4*)(pr + 4);
    v[10] = *(const floatx4*)(pr + 32); v[11] = *(const floatx4*)(pr + 36);
}

__global__ __launch_bounds__(256, 2) void polyconv_kernel(
    const float* __restrict__ x,
    const int* __restrict__ lidx,
    const int* __restrict__ ridx,
    const float* __restrict__ W,
    const float* __restrict__ bias,
    float* __restrict__ out,
    int n_tiles, int total_waves)
{
    const int lane = threadIdx.x & 63;
    const int wave_id = blockIdx.x * (blockDim.x >> 6) + (threadIdx.x >> 6);
    const int col  = lane & 15;
    const int quad = lane >> 4;

    bf16x8 bfrag[6][4];
    floatx4 bi4[4];
    load_wfrags(bfrag, bi4, W, bias, col, quad);

    const int stride = total_waves;
    int t = wave_id;
    if (t >= n_tiles) return;

    floatx4 va[12], vb[12];
    int li_n = 0, ri_n = 0;

    {
        int item = t * 16 + col;
        int li = lidx[item], ri = ridx[item];
        issue_gather_f32(va, x, item, li, ri, quad);
    }
    int t1 = t + stride;
    if (t1 < n_tiles) { li_n = lidx[t1 * 16 + col]; ri_n = ridx[t1 * 16 + col]; }

    while (true) {
        if (t1 < n_tiles) {
            issue_gather_f32(vb, x, t1 * 16 + col, li_n, ri_n, quad);
            int t2 = t1 + stride;
            if (t2 < n_tiles) { li_n = lidx[t2 * 16 + col]; ri_n = ridx[t2 * 16 + col]; }
        }
        {
            bf16x8 af[6];
#pragma unroll
            for (int ks = 0; ks < 6; ++ks) {
                floatx4 a0 = va[2 * ks], a1 = va[2 * ks + 1];
                bf16x8 f;
                f[0] = (__bf16)a0[0]; f[1] = (__bf16)a0[1];
                f[2] = (__bf16)a0[2]; f[3] = (__bf16)a0[3];
                f[4] = (__bf16)a1[0]; f[5] = (__bf16)a1[1];
                f[6] = (__bf16)a1[2]; f[7] = (__bf16)a1[3];
                af[ks] = f;
            }
            compute_store_swapped(af, bfrag, bi4, out, t * 16, col, quad);
        }
        t = t1; t1 += stride;
        if (t >= n_tiles) break;

        if (t1 < n_tiles) {
            issue_gather_f32(va, x, t1 * 16 + col, li_n, ri_n, quad);
            int t2 = t1 + stride;
            if (t2 < n_tiles) { li_n = lidx[t2 * 16 + col]; ri_n = ridx[t2 * 16 + col]; }
        }
        {
            bf16x8 af[6];
#pragma unroll
            for (int ks = 0; ks < 6; ++ks) {
                floatx4 a0 = vb[2 * ks], a1 = vb[2 * ks + 1];
                bf16x8 f;
                f[0] = (__bf16)a0[0]; f[1] = (__bf16)a0[1];
                f[2] = (__bf16)a0[2]; f[3] = (__bf16)a0[3];
                f[4] = (__bf16)a1[0]; f[5] = (__bf16)a1[1];
                f[6] = (__bf16)a1[2]; f[7] = (__bf16)a1[3];
                af[ks] = f;
            }
            compute_store_swapped(af, bfrag, bi4, out, t * 16, col, quad);
        }
        t = t1; t1 += stride;
        if (t >= n_tiles) break;
    }
}

extern "C" void kernel_launch(void* const* d_in, const int* in_sizes, int n_in,
                              void* d_out, int out_size, void* d_ws, size_t ws_size,
                              hipStream_t stream) {
    const float* x  = (const float*)d_in[0];
    const int*   li = (const int*)d_in[1];
    const int*   ri = (const int*)d_in[2];
    const float* W  = (const float*)d_in[3];
    const float* b  = (const float*)d_in[4];
    float* out = (float*)d_out;

    const int n = in_sizes[1];                         // N = 1,000,000
    const int n_tiles = n / 16;                        // 62500
    const size_t need = (size_t)n * D * sizeof(__bf16); // 128 MB
    const long n8 = (long)n * D / 8;                   // 8M bf16x8 chunks

    if (d_ws != nullptr && ws_size >= need) {
        __bf16* xb = (__bf16*)d_ws;

        // Co-resident grid size for the cooperative launch (MI355X: 256 CUs).
        static int coop_blocks = -1;
        if (coop_blocks < 0) {
            int maxb = 0;
            if (hipOccupancyMaxActiveBlocksPerMultiprocessor(
                    &maxb, polyconv_fused, 256, 0) != hipSuccess || maxb < 1)
                maxb = 2;   // __launch_bounds__(256,2) guarantees 2 blocks/CU
            if (maxb > 4) maxb = 4;
            coop_blocks = 256 * maxb;
        }

        int blocks = coop_blocks;
        int total_waves = blocks * 4;
        void* args[] = {(void*)&x, (void*)&li, (void*)&ri, (void*)&W, (void*)&b,
                        (void*)&out, (void*)&xb, (void*)&n_tiles,
                        (void*)&total_waves, (void*)&n8};
        hipError_t e = hipLaunchCooperativeKernel(
            (const void*)polyconv_fused, dim3(blocks), dim3(256), args, 0, stream);
        if (e == hipSuccess) return;

        (void)hipGetLastError();   // clear error state, fall back to two-kernel path
        convert_x_bf16<<<2048, 256, 0, stream>>>(x, xb, n8);
        const int blocks2 = 1024;
        polyconv_bf16<<<blocks2, 256, 0, stream>>>(xb, li, ri, W, b, out,
                                                   n_tiles, blocks2 * 4);
    } else {
        const int blocks = 1024;
        polyconv_kernel<<<blocks, 256, 0, stream>>>(x, li, ri, W, b, out,
                                                    n_tiles, blocks * 4);
    }
}